// Round 6
// baseline (106.748 us; speedup 1.0000x reference)
//
#include <hip/hip_runtime.h>

namespace {

constexpr int B = 4, LX = 512, LM = 512, D = 256;
// Fold 2*log2(e) into the projection: tanh(u) = 1 - 2/(1+exp2(KSCALE*u))
constexpr float KSCALE = 2.8853900817779268f;
// exp2-arg clamp: E in [2^-7.5, 2^7.5] -> T=1+E1E2 <= ~2^15 -> 8-term den <= 2^120.
// Saturation error <= 1-tanh(7.5/KSCALE)=0.011 per term -> absmax ~0.1 << 199.7.
constexpr float CLAMP = 7.5f;

typedef __attribute__((ext_vector_type(8))) short short8;
typedef __attribute__((ext_vector_type(4))) float f32x4;
typedef __attribute__((ext_vector_type(2))) float f32x2;

__device__ __forceinline__ unsigned bfbits(float f) {
    unsigned u = __float_as_uint(f);
    u += 0x7FFFu + ((u >> 16) & 1u);
    return u >> 16;
}
__device__ __forceinline__ int pack2(float a, float b) {
    return (int)(bfbits(a) | (bfbits(b) << 16));
}

// ---------------------------------------------------------------------------
// proj_mfma: combined GEMM (rows 0..2047 = x@W1^T+b1, 2048..4095 = mem@W2^T),
// epilogue writes E = exp2(clamp(KSCALE*y)) as f32 PAIRS:
//   Ef[ (((row>>5)*16 + (row&15))*256 + e)*2 + (row&16 ? 1 : 0) ]
// i.e. float2{half0 row, half1 row} per (pair,e). 32x64 tile/block,
// MFMA 16x16x32 bf16 via LDS staging. Grid (128,4) = 2/CU.
// ---------------------------------------------------------------------------
__global__ __launch_bounds__(256) void proj_mfma(
    const float* __restrict__ x, const float* __restrict__ mem,
    const float* __restrict__ W1, const float* __restrict__ b1v,
    const float* __restrict__ W2,
    float* __restrict__ E1f, float* __restrict__ E2f)
{
    const int tid = threadIdx.x;
    const int m0c = blockIdx.x * 32;
    const int e0  = blockIdx.y * 64;
    const int z   = m0c >= 2048;
    const int r0  = z ? (m0c - 2048) : m0c;
    const float* __restrict__ A = (z ? mem : x) + (size_t)r0 * D;
    const float* __restrict__ W = z ? W2 : W1;
    float* __restrict__ Ef = z ? E2f : E1f;

    __shared__ short sA[32][40];
    __shared__ short sW[64][40];

    const int wv = tid >> 6, lane = tid & 63;
    const int lr = lane & 15, quad = lane >> 4;
    const int g   = wv & 1;              // row half (0: rows 0-15, 1: 16-31)
    const int cg0 = (wv >> 1) * 2;
    const int srA = tid >> 3;
    const int scA = (tid & 7) * 4;

    f32x4 acc0 = {0.f, 0.f, 0.f, 0.f};
    f32x4 acc1 = {0.f, 0.f, 0.f, 0.f};

    for (int kc = 0; kc < D; kc += 32) {
        float4 av = *(const float4*)&A[(size_t)srA * D + kc + scA];
        float4 w0 = *(const float4*)&W[(size_t)(e0 + srA) * D + kc + scA];
        float4 w1 = *(const float4*)&W[(size_t)(e0 + 32 + srA) * D + kc + scA];
        __syncthreads();
        *(int2*)&sA[srA][scA]      = make_int2(pack2(av.x, av.y), pack2(av.z, av.w));
        *(int2*)&sW[srA][scA]      = make_int2(pack2(w0.x, w0.y), pack2(w0.z, w0.w));
        *(int2*)&sW[srA + 32][scA] = make_int2(pack2(w1.x, w1.y), pack2(w1.z, w1.w));
        __syncthreads();
        short8 af  = *(const short8*)&sA[g * 16 + lr][quad * 8];
        short8 bf0 = *(const short8*)&sW[cg0 * 16 + lr][quad * 8];
        short8 bf1 = *(const short8*)&sW[cg0 * 16 + 16 + lr][quad * 8];
        acc0 = __builtin_amdgcn_mfma_f32_16x16x32_bf16(af, bf0, acc0, 0, 0, 0);
        acc1 = __builtin_amdgcn_mfma_f32_16x16x32_bf16(af, bf1, acc1, 0, 0, 0);
    }

    const float bias0 = z ? 0.f : b1v[e0 + cg0 * 16 + lr];
    const float bias1 = z ? 0.f : b1v[e0 + cg0 * 16 + 16 + lr];
    const int ec0 = e0 + cg0 * 16 + lr;
#pragma unroll
    for (int reg = 0; reg < 4; ++reg) {
        const int pair = quad * 4 + reg;           // row within half
        const size_t base = (size_t)((r0 >> 5) * 16 + pair) * 256;
        float a0 = KSCALE * (acc0[reg] + bias0);
        float a1 = KSCALE * (acc1[reg] + bias1);
        a0 = fminf(fmaxf(a0, -CLAMP), CLAMP);
        a1 = fminf(fmaxf(a1, -CLAMP), CLAMP);
        Ef[(base + ec0) * 2 + g]      = __builtin_amdgcn_exp2f(a0);
        Ef[(base + ec0 + 16) * 2 + g] = __builtin_amdgcn_exp2f(a1);
    }
}

// ---------------------------------------------------------------------------
// tanh_score v5: S = sumWt - 2*sum_d Wt[d]/(1+E1E2), mask at write.
// f32-pair E: float2 = {row, row+16} -> pk-ready operands, ZERO unpack ops.
// 32(x) x 64(m) tile, 256 thr; thread = x-pair(ty) x 2 m-pairs(tx, tx+16),
// both orientations via f32x2 lane-swap (op_sel) -> 8 outputs/thread.
// 8-term common denominator: 1 rcp per 8 d per output-pair.
// D-chunks of 128 pairs; LDS row stride 268 f32 (1072 B): 16B-aligned,
// B-row bank walk 12 -> max 2-way (free, m136). Grid (8,16,4) = 2/CU.
// ---------------------------------------------------------------------------
__global__ __launch_bounds__(256) void tanh_score_kernel(
    const float* __restrict__ E1f, const float* __restrict__ E2f,
    const float* __restrict__ Wt, const int* __restrict__ mask,
    float* __restrict__ out)
{
    const int tid = threadIdx.x;
    const int b  = blockIdx.z;
    const int x0 = blockIdx.y * 32;
    const int m0 = blockIdx.x * 64;
    const int xt = (b * LX + x0) >> 5;   // 32-row tile index into E1f
    const int mt = (b * LM + m0) >> 5;   // 32-row tile base into E2f

    constexpr int ST = 268;              // LDS row stride in floats
    __shared__ float sA[16 * ST];
    __shared__ float sB[32 * ST];

    const int tx = tid & 15, ty = tid >> 4;
    const int pA = tid >> 4, cA = (tid & 15) * 16;  // A staging: 16 thr/row, 64 B
    const int rB = tid >> 3, cB = (tid & 7) * 32;   // B staging: 8 thr/row, 128 B
    // global float base of this thread's staging row (full row = 512 floats)
    const float* gA = E1f + (size_t)(xt * 16 + pA) * 512;
    const float* gB = E2f + (size_t)((mt + (rB >> 4)) * 16 + (rB & 15)) * 512;

    float sumW = 0.f;
#pragma unroll
    for (int i = 0; i < 256; i += 4) {
        const float4 w = *(const float4*)&Wt[i];
        sumW += (w.x + w.y) + (w.z + w.w);
    }

    f32x2 acc01s = {0.f, 0.f}, acc01w = {0.f, 0.f};
    f32x2 acc23s = {0.f, 0.f}, acc23w = {0.f, 0.f};
    const f32x2 one2 = {1.f, 1.f};

    for (int c = 0; c < 2; ++c) {
        const int fB = c * 256;          // chunk base in floats (128 pairs)
        float4 A0 = *(const float4*)(gA + fB + cA);
        float4 A1 = *(const float4*)(gA + fB + cA + 4);
        float4 A2 = *(const float4*)(gA + fB + cA + 8);
        float4 A3 = *(const float4*)(gA + fB + cA + 12);
        float4 B0 = *(const float4*)(gB + fB + cB);
        float4 B1 = *(const float4*)(gB + fB + cB + 4);
        float4 B2 = *(const float4*)(gB + fB + cB + 8);
        float4 B3 = *(const float4*)(gB + fB + cB + 12);
        float4 B4 = *(const float4*)(gB + fB + cB + 16);
        float4 B5 = *(const float4*)(gB + fB + cB + 20);
        float4 B6 = *(const float4*)(gB + fB + cB + 24);
        float4 B7 = *(const float4*)(gB + fB + cB + 28);
        __syncthreads();
        *(float4*)&sA[pA * ST + cA + 0]  = A0;
        *(float4*)&sA[pA * ST + cA + 4]  = A1;
        *(float4*)&sA[pA * ST + cA + 8]  = A2;
        *(float4*)&sA[pA * ST + cA + 12] = A3;
        *(float4*)&sB[rB * ST + cB + 0]  = B0;
        *(float4*)&sB[rB * ST + cB + 4]  = B1;
        *(float4*)&sB[rB * ST + cB + 8]  = B2;
        *(float4*)&sB[rB * ST + cB + 12] = B3;
        *(float4*)&sB[rB * ST + cB + 16] = B4;
        *(float4*)&sB[rB * ST + cB + 20] = B5;
        *(float4*)&sB[rB * ST + cB + 24] = B6;
        *(float4*)&sB[rB * ST + cB + 28] = B7;
        __syncthreads();

#pragma unroll 1
        for (int dp = 0; dp < 128; dp += 8) {      // 8 d-pairs per iter
            const int d2 = dp * 2;
            const f32x4 va0 = *(const f32x4*)&sA[ty * ST + d2];
            const f32x4 va1 = *(const f32x4*)&sA[ty * ST + d2 + 4];
            const f32x4 va2 = *(const f32x4*)&sA[ty * ST + d2 + 8];
            const f32x4 va3 = *(const f32x4*)&sA[ty * ST + d2 + 12];
            const f32x4 vp0 = *(const f32x4*)&sB[tx * ST + d2];
            const f32x4 vp1 = *(const f32x4*)&sB[tx * ST + d2 + 4];
            const f32x4 vp2 = *(const f32x4*)&sB[tx * ST + d2 + 8];
            const f32x4 vp3 = *(const f32x4*)&sB[tx * ST + d2 + 12];
            const f32x4 vq0 = *(const f32x4*)&sB[(16 + tx) * ST + d2];
            const f32x4 vq1 = *(const f32x4*)&sB[(16 + tx) * ST + d2 + 4];
            const f32x4 vq2 = *(const f32x4*)&sB[(16 + tx) * ST + d2 + 8];
            const f32x4 vq3 = *(const f32x4*)&sB[(16 + tx) * ST + d2 + 12];
            const float4 w0 = *(const float4*)&Wt[c * 128 + dp];     // uniform
            const float4 w1 = *(const float4*)&Wt[c * 128 + dp + 4];

            const f32x2 a_[8] = {{va0.x, va0.y}, {va0.z, va0.w},
                                 {va1.x, va1.y}, {va1.z, va1.w},
                                 {va2.x, va2.y}, {va2.z, va2.w},
                                 {va3.x, va3.y}, {va3.z, va3.w}};
            const f32x2 p_[8] = {{vp0.x, vp0.y}, {vp0.z, vp0.w},
                                 {vp1.x, vp1.y}, {vp1.z, vp1.w},
                                 {vp2.x, vp2.y}, {vp2.z, vp2.w},
                                 {vp3.x, vp3.y}, {vp3.z, vp3.w}};
            const f32x2 q_[8] = {{vq0.x, vq0.y}, {vq0.z, vq0.w},
                                 {vq1.x, vq1.y}, {vq1.z, vq1.w},
                                 {vq2.x, vq2.y}, {vq2.z, vq2.w},
                                 {vq3.x, vq3.y}, {vq3.z, vq3.w}};
            const float wv[8] = {w0.x, w0.y, w0.z, w0.w, w1.x, w1.y, w1.z, w1.w};

#define SPL(s)  ((f32x2){(s), (s)})
#define FMA2(A_, B_, C_) __builtin_elementwise_fma((A_), (B_), (C_))
            // 8-term common denominator over a float2 lane-pair:
            // acc += (sum_j wv[j]/(1+a_j*b_j)) elementwise, ONE rcp per lane.
#define OCT(BX, accv) { \
    const f32x2 T0 = FMA2(a_[0], BX(0), one2), T1 = FMA2(a_[1], BX(1), one2); \
    const f32x2 T2 = FMA2(a_[2], BX(2), one2), T3 = FMA2(a_[3], BX(3), one2); \
    const f32x2 T4 = FMA2(a_[4], BX(4), one2), T5 = FMA2(a_[5], BX(5), one2); \
    const f32x2 T6 = FMA2(a_[6], BX(6), one2), T7 = FMA2(a_[7], BX(7), one2); \
    const f32x2 L0 = T0 * T1, L1 = T2 * T3, L2 = T4 * T5, L3 = T6 * T7;       \
    const f32x2 Q0 = L0 * L1, Q1 = L2 * L3;                                   \
    const f32x2 den = Q0 * Q1;                                                \
    const f32x2 n0 = FMA2(SPL(wv[0]), T1, SPL(wv[1]) * T0);                   \
    const f32x2 n1 = FMA2(SPL(wv[2]), T3, SPL(wv[3]) * T2);                   \
    const f32x2 n2 = FMA2(SPL(wv[4]), T5, SPL(wv[5]) * T4);                   \
    const f32x2 n3 = FMA2(SPL(wv[6]), T7, SPL(wv[7]) * T6);                   \
    const f32x2 u0 = FMA2(n0, L1, n1 * L0), u1 = FMA2(n2, L3, n3 * L2);       \
    const f32x2 N  = FMA2(u0, Q1, u1 * Q0);                                   \
    f32x2 r; r.x = __builtin_amdgcn_rcpf(den.x);                              \
             r.y = __builtin_amdgcn_rcpf(den.y);                              \
    (accv) = FMA2(N, r, (accv)); }

#define BP(i)  (p_[i])
#define BPS(i) (__builtin_shufflevector(p_[i], p_[i], 1, 0))
#define BQ(i)  (q_[i])
#define BQS(i) (__builtin_shufflevector(q_[i], q_[i], 1, 0))
            OCT(BP,  acc01s)   // (xA,m+tx)    , (xB,m+16+tx)
            OCT(BPS, acc01w)   // (xA,m+16+tx) , (xB,m+tx)
            OCT(BQ,  acc23s)   // (xA,m+32+tx) , (xB,m+48+tx)
            OCT(BQS, acc23w)   // (xA,m+48+tx) , (xB,m+32+tx)
#undef BP
#undef BPS
#undef BQ
#undef BQS
#undef OCT
#undef FMA2
#undef SPL
        }
    }

    const int xA = x0 + ty, xB = x0 + 16 + ty;
    const int mmv[4] = {m0 + tx, m0 + 16 + tx, m0 + 32 + tx, m0 + 48 + tx};
    const float vA[4] = {acc01s.x, acc01w.x, acc23s.x, acc23w.x};
    const float vB[4] = {acc01w.y, acc01s.y, acc23w.y, acc23s.y};
#pragma unroll
    for (int k = 0; k < 4; ++k) {
        const bool keep = mask[b * LM + mmv[k]] != 0;
        out[((size_t)b * LX + xA) * LM + mmv[k]] =
            keep ? (sumW - 2.f * vA[k]) : -10000.f;
        out[((size_t)b * LX + xB) * LM + mmv[k]] =
            keep ? (sumW - 2.f * vB[k]) : -10000.f;
    }
}

} // namespace

extern "C" void kernel_launch(void* const* d_in, const int* in_sizes, int n_in,
                              void* d_out, int out_size, void* d_ws, size_t ws_size,
                              hipStream_t stream)
{
    const float* x    = (const float*)d_in[0];
    const float* mem  = (const float*)d_in[1];
    const int*   mask = (const int*)d_in[2];
    const float* W1   = (const float*)d_in[3];
    const float* b1   = (const float*)d_in[4];
    const float* W2   = (const float*)d_in[5];
    const float* Wt   = (const float*)d_in[6];
    float* out = (float*)d_out;

    float* E1f = (float*)d_ws;                        // (64 tiles,16,256) f32 pairs
    float* E2f = E1f + (size_t)(B * LX / 32) * 16 * 512;

    proj_mfma<<<dim3(128, 4), 256, 0, stream>>>(x, mem, W1, b1, W2, E1f, E2f);

    tanh_score_kernel<<<dim3(LM / 64, LX / 32, B), 256, 0, stream>>>(
        E1f, E2f, Wt, mask, out);
}